// Round 9
// baseline (124.351 us; speedup 1.0000x reference)
//
#include <hip/hip_runtime.h>
#include <cfloat>

// Problem dims (fixed by reference)
#define BB   256   // batch
#define DIM  512
#define NN   196
#define BT   16    // b-tile in prep kernel
#define IT   32    // i-tile in prep kernel

// ============================================================================
// ROUND 9 = ATTRIBUTION ROUND. Kernels are byte-identical to round 6 (best,
// 37.1 us). prep is launched with grid.z=6 and read with grid.y=3 — each
// replica does identical work (identical-value write races are benign and
// deterministic). Purpose: (a) slope gives the prep/read time split,
// (b) max(6P,3R) > 58 us guarantees at least one of our kernels surfaces
// in the rocprof top-5 WITH counters (they've been hidden under ~58-us
// harness fills for 8 rounds).
// ============================================================================

// ---------------------------------------------------------------------------
// Kernel 1: prep — w[b,i] = (mem[b,i] + b_mem[i]) * v1[b,i] + v2[b,i]
// (byte-identical to round 6; blockIdx.z intentionally unused)
// ---------------------------------------------------------------------------
__global__ __launch_bounds__(1024, 1) void prep_kernel(
    const float* __restrict__ memory,    // (2,BB,DIM)
    const float* __restrict__ control,   // (2,BB,DIM)
    const float* __restrict__ W_mem,     // (DIM,DIM) row-major [k][i]
    const float* __restrict__ b_mem,     // (DIM)
    const float* __restrict__ W_concat,  // (2*DIM, DIM) row-major [c][j]
    const float* __restrict__ W_attn,    // (DIM,1)
    float* __restrict__ w_out)           // (BB, DIM)
{
    __shared__ float4 MU[8][DIM];    // 64 KB
    __shared__ float  buf[12288];    // 48 KB

    const int tid = threadIdx.x;
    const int il  = tid & 31;
    const int bg  = (tid >> 5) & 3;
    const int kg  = tid >> 7;
    const int b0  = blockIdx.x * BT;
    const int i0  = blockIdx.y * IT;

    const float* mem_in = memory  + (size_t)BB * DIM;
    const float* ctl_in = control + (size_t)BB * DIM;

    #pragma unroll
    for (int p4 = 0; p4 < 4; ++p4) {
        const int idx = p4 * 1024 + tid;
        const int k   = idx & 511;
        const int pp  = idx >> 9;
        const int bb  = b0 + pp * 2;
        const float wa = W_attn[k];
        MU[pp][k] = make_float4(
            mem_in[(size_t)bb       * DIM + k],
            ctl_in[(size_t)bb       * DIM + k] * wa,
            mem_in[(size_t)(bb + 1) * DIM + k],
            ctl_in[(size_t)(bb + 1) * DIM + k] * wa);
    }

    float am[4] = {0.f, 0.f, 0.f, 0.f};
    float a1[4] = {0.f, 0.f, 0.f, 0.f};
    float a2[4] = {0.f, 0.f, 0.f, 0.f};

    const int sr = tid >> 5;
    const int sc = tid & 15;
    const int h  = (tid >> 4) & 1;

    for (int kt = 0; kt < DIM; kt += 64) {
        __syncthreads();
        {
            const float4 q = *(const float4*)&W_concat[
                (size_t)(h * DIM + i0 + sr) * DIM + kt + sc * 4];
            const int kb = sc * 4;
            buf[((kb + 0) * 33 + sr) * 2 + h] = q.x;
            buf[((kb + 1) * 33 + sr) * 2 + h] = q.y;
            buf[((kb + 2) * 33 + sr) * 2 + h] = q.z;
            buf[((kb + 3) * 33 + sr) * 2 + h] = q.w;
        }
        __syncthreads();

        #pragma unroll
        for (int kk = 0; kk < 8; ++kk) {
            const int kl = kg * 8 + kk;
            const int k  = kt + kl;
            const float  wm  = W_mem[(size_t)k * DIM + i0 + il];
            const float2 c   = ((const float2*)buf)[kl * 33 + il];
            const float4 mu0 = MU[bg * 2 + 0][k];
            const float4 mu1 = MU[bg * 2 + 1][k];
            am[0] = fmaf(mu0.x, wm,  am[0]);
            a1[0] = fmaf(mu0.y, c.x, a1[0]);
            a2[0] = fmaf(mu0.y, c.y, a2[0]);
            am[1] = fmaf(mu0.z, wm,  am[1]);
            a1[1] = fmaf(mu0.w, c.x, a1[1]);
            a2[1] = fmaf(mu0.w, c.y, a2[1]);
            am[2] = fmaf(mu1.x, wm,  am[2]);
            a1[2] = fmaf(mu1.y, c.x, a1[2]);
            a2[2] = fmaf(mu1.y, c.y, a2[2]);
            am[3] = fmaf(mu1.z, wm,  am[3]);
            a1[3] = fmaf(mu1.w, c.x, a1[3]);
            a2[3] = fmaf(mu1.w, c.y, a2[3]);
        }
    }

    __syncthreads();
    #pragma unroll
    for (int j = 0; j < 4; ++j) {
        const int row = (kg * 16 + bg * 4 + j) * 32 + il;
        buf[row]        = am[j];
        buf[4096 + row] = a1[j];
        buf[8192 + row] = a2[j];
    }
    __syncthreads();
    if (tid < 512) {
        const int b = tid >> 5, ii = tid & 31;
        float sm = 0.f, s1 = 0.f, s2 = 0.f;
        #pragma unroll
        for (int t = 0; t < 8; ++t) {
            const int row = (t * 16 + b) * 32 + ii;
            sm += buf[row];
            s1 += buf[4096 + row];
            s2 += buf[8192 + row];
        }
        w_out[(size_t)(b0 + b) * DIM + i0 + ii] = (sm + b_mem[i0 + ii]) * s1 + s2;
    }
}

// ---------------------------------------------------------------------------
// Kernel 2: per-b streaming pass over know (float4, 16 waves/block).
// (byte-identical to round 6; blockIdx.y intentionally unused)
// ---------------------------------------------------------------------------
__global__ __launch_bounds__(1024) void read_kernel(
    const float* __restrict__ know,  // (BB, DIM, NN)
    const float* __restrict__ w,     // (BB, DIM)
    float* __restrict__ out)         // (BB, NN)
{
    __shared__ float  w_s[DIM];
    __shared__ float4 part_lg[16][50];
    __shared__ float4 part_ks[16][50];
    __shared__ float  tmp[256];
    __shared__ float  bc[2];

    const int tx  = threadIdx.x;       // 0..63 (lane)
    const int ty  = threadIdx.y;       // 0..15 (wave)
    const int tid = ty * 64 + tx;
    const int b   = blockIdx.x;

    if (tid < DIM) w_s[tid] = w[(size_t)b * DIM + tid];
    __syncthreads();

    float4 lg = make_float4(0.f, 0.f, 0.f, 0.f);
    float4 ks = make_float4(0.f, 0.f, 0.f, 0.f);
    if (tx < 49) {
        const float4* kp = (const float4*)(know + (size_t)b * DIM * NN) + (size_t)(ty * 32) * 49 + tx;
        const float*  wp = w_s + ty * 32;
        #pragma unroll 8
        for (int dd = 0; dd < 32; ++dd) {
            const float4 kv = kp[(size_t)dd * 49];
            const float  wv = wp[dd];
            lg.x = fmaf(kv.x, wv, lg.x); lg.y = fmaf(kv.y, wv, lg.y);
            lg.z = fmaf(kv.z, wv, lg.z); lg.w = fmaf(kv.w, wv, lg.w);
            ks.x += kv.x; ks.y += kv.y; ks.z += kv.z; ks.w += kv.w;
        }
        part_lg[ty][tx] = lg;
        part_ks[ty][tx] = ks;
    }
    __syncthreads();

    float lgn = 0.f, ksn = 0.f;
    if (tid < NN) {
        const int ng = tid >> 2, j = tid & 3;
        #pragma unroll
        for (int t = 0; t < 16; ++t) {
            lgn += ((const float*)&part_lg[t][ng])[j];
            ksn += ((const float*)&part_ks[t][ng])[j];
        }
    }

    if (tid < 256) tmp[tid] = (tid < NN) ? lgn : -FLT_MAX;
    __syncthreads();
    if (tid < 64) {
        float m = fmaxf(fmaxf(tmp[tid], tmp[tid + 64]),
                        fmaxf(tmp[tid + 128], tmp[tid + 192]));
        #pragma unroll
        for (int o = 32; o; o >>= 1) m = fmaxf(m, __shfl_down(m, o));
        if (tid == 0) bc[0] = m;
    }
    __syncthreads();

    const float e = (tid < NN) ? __expf(lgn - bc[0]) : 0.f;
    if (tid < 256) tmp[tid] = e;
    __syncthreads();
    if (tid < 64) {
        float s = tmp[tid] + tmp[tid + 64] + tmp[tid + 128] + tmp[tid + 192];
        #pragma unroll
        for (int o = 32; o; o >>= 1) s += __shfl_down(s, o);
        if (tid == 0) bc[1] = s;
    }
    __syncthreads();

    if (tid < NN) out[(size_t)b * NN + tid] = e / bc[1] * ksn;
}

// ---------------------------------------------------------------------------
extern "C" void kernel_launch(void* const* d_in, const int* in_sizes, int n_in,
                              void* d_out, int out_size, void* d_ws, size_t ws_size,
                              hipStream_t stream) {
    const float* memory   = (const float*)d_in[0];
    const float* know     = (const float*)d_in[1];
    const float* control  = (const float*)d_in[2];
    const float* W_mem    = (const float*)d_in[3];
    const float* b_mem    = (const float*)d_in[4];
    const float* W_concat = (const float*)d_in[5];
    // d_in[6] = b_concat : uniform over n -> softmax-invariant, unused
    const float* W_attn   = (const float*)d_in[7];
    // d_in[8] = b_attn   : same, unused
    float* w_ws = (float*)d_ws;          // (BB, DIM) = 512 KB scratch
    float* outp = (float*)d_out;         // (BB, NN) f32

    // ATTRIBUTION: 6x prep replicas (grid.z), 3x read replicas (grid.y).
    // Replicas do identical work / identical-value writes -> deterministic.
    prep_kernel<<<dim3(BB / BT, DIM / IT, 6), dim3(1024), 0, stream>>>(
        memory, control, W_mem, b_mem, W_concat, W_attn, w_ws);
    read_kernel<<<dim3(BB, 3), dim3(64, 16), 0, stream>>>(know, w_ws, outp);
}

// Round 10
// 49.627 us; speedup vs baseline: 2.5057x; 2.5057x over previous
//
#include <hip/hip_runtime.h>
#include <cfloat>

// Problem dims (fixed by reference)
#define BB   256   // batch
#define DIM  512
#define NN   196
#define BT   8     // b-tile in prep kernel
#define IT   32    // i-tile in prep kernel

// ---------------------------------------------------------------------------
// Kernel 1: prep — w[b,i] = (mem[b,i] + b_mem[i]) * v1[b,i] + v2[b,i]
//   mem[b,i] = sum_k memory[-1][b,k] * W_mem[k,i]
//   v1[b,i]  = sum_k u[b,k] * W_concat[i,     k]   (u = control[-1]*W_attn)
//   v2[b,i]  = sum_k u[b,k] * W_concat[DIM+i, k]
//
// r9 counters: old prep = 1 block/CU (112 KB LDS), VALUBusy 45%, Occ 42%,
// 4.7M LDS bank conflicts. Fix: grid (BB/8, DIM/32) = 512 blocks x 512 thr
// -> 2 blocks/CU co-resident (barriers overlap); MU LDS array removed (m/u
// read per-thread from global as wave-broadcast float4s, L2-hot); LDS 17 KB.
// Thread (il = tid&31, kg = tid>>5): 4-k slice of each 64-k chunk, one i,
// all 8 b -> 24 accumulators. Epilogue reduces 16 kg-partials per acc-type.
// ---------------------------------------------------------------------------
__global__ __launch_bounds__(512, 4) void prep_kernel(
    const float* __restrict__ memory,    // (2,BB,DIM)
    const float* __restrict__ control,   // (2,BB,DIM)
    const float* __restrict__ W_mem,     // (DIM,DIM) row-major [k][i]
    const float* __restrict__ b_mem,     // (DIM)
    const float* __restrict__ W_concat,  // (2*DIM, DIM) row-major [c][j]
    const float* __restrict__ W_attn,    // (DIM,1)
    float* __restrict__ w_out)           // (BB, DIM)
{
    // floats: WT1 = [0,2112), WT2 = [2112,4224)  (64 k x 33-padded x {c1,c2})
    // epilogue reuses [0,4096) as P[16 kg][8 b][32 il]
    __shared__ float lds[4224];          // 16.9 KB

    const int tid = threadIdx.x;
    const int il  = tid & 31;          // i within tile
    const int kg  = tid >> 5;          // 0..15 k-slice owner (4 k each)
    const int b0  = blockIdx.x * BT;
    const int i0  = blockIdx.y * IT;

    const float* mem_in = memory  + (size_t)BB * DIM;  // memory[-1]
    const float* ctl_in = control + (size_t)BB * DIM;  // control[-1]

    float am[8] = {0,0,0,0,0,0,0,0};
    float a1[8] = {0,0,0,0,0,0,0,0};
    float a2[8] = {0,0,0,0,0,0,0,0};

    // staging coords: h = which matrix, (sr, sc) = row / float4-col
    const int h  = tid >> 8;           // 0 -> W1, 1 -> W2
    const int sr = (tid >> 3) & 31;    // i row 0..31
    const int sc = tid & 7;            // f4 col 0..7 (also sc+8)
    float* WT1 = lds;
    float* WT2 = lds + 2112;
    float* WTh = h ? WT2 : WT1;

    for (int kt = 0; kt < DIM; kt += 64) {
        __syncthreads();   // previous chunk's compute done

        // stage W_concat chunk transposed: rows i0..i0+31 (W1) / +DIM (W2),
        // cols kt..kt+63.  512 thr x 2 float4 = 1024 f4.
        {
            const float* wrow = W_concat + (size_t)(h * DIM + i0 + sr) * DIM + kt;
            const float4 qa = *(const float4*)(wrow + sc * 4);
            const float4 qb = *(const float4*)(wrow + (sc + 8) * 4);
            const float* qaf = (const float*)&qa;
            const float* qbf = (const float*)&qb;
            #pragma unroll
            for (int j = 0; j < 4; ++j) {
                WTh[(sc * 4 + j) * 33 + sr]       = qaf[j];
                WTh[((sc + 8) * 4 + j) * 33 + sr] = qbf[j];
            }
        }
        __syncthreads();

        // this thread's 4-k slice
        const int kb = kg * 4;
        float wm[4], c1[4], c2[4];
        #pragma unroll
        for (int j = 0; j < 4; ++j) {
            const int kl = kb + j;
            wm[j] = W_mem[(size_t)(kt + kl) * DIM + i0 + il];  // coalesced 128B
            c1[j] = WT1[kl * 33 + il];                         // 2-way max
            c2[j] = WT2[kl * 33 + il];
        }
        const float4 wa4 = *(const float4*)(W_attn + kt + kb); // broadcast
        const float* waf = (const float*)&wa4;

        #pragma unroll
        for (int b = 0; b < 8; ++b) {
            // wave-broadcast float4 loads (same addr across il), L2-hot
            const float4 mq = *(const float4*)(mem_in + (size_t)(b0 + b) * DIM + kt + kb);
            const float4 cq = *(const float4*)(ctl_in + (size_t)(b0 + b) * DIM + kt + kb);
            const float* mqf = (const float*)&mq;
            const float* cqf = (const float*)&cq;
            #pragma unroll
            for (int j = 0; j < 4; ++j) {
                const float u = cqf[j] * waf[j];
                am[b] = fmaf(mqf[j], wm[j], am[b]);
                a1[b] = fmaf(u, c1[j], a1[b]);
                a2[b] = fmaf(u, c2[j], a2[b]);
            }
        }
    }

    // ---- epilogue: reduce 16 kg-partials, one acc-type at a time ----
    float sm = 0.f, s1 = 0.f, s2 = 0.f;
    const int rb = tid >> 5;     // reducer's b (tid<256)
    const int ri = tid & 31;     // reducer's i

    __syncthreads();
    #pragma unroll
    for (int b = 0; b < 8; ++b) lds[(kg * 8 + b) * 32 + il] = am[b];
    __syncthreads();
    if (tid < 256) {
        #pragma unroll
        for (int t = 0; t < 16; ++t) sm += lds[(t * 8 + rb) * 32 + ri];
    }
    __syncthreads();
    #pragma unroll
    for (int b = 0; b < 8; ++b) lds[(kg * 8 + b) * 32 + il] = a1[b];
    __syncthreads();
    if (tid < 256) {
        #pragma unroll
        for (int t = 0; t < 16; ++t) s1 += lds[(t * 8 + rb) * 32 + ri];
    }
    __syncthreads();
    #pragma unroll
    for (int b = 0; b < 8; ++b) lds[(kg * 8 + b) * 32 + il] = a2[b];
    __syncthreads();
    if (tid < 256) {
        #pragma unroll
        for (int t = 0; t < 16; ++t) s2 += lds[(t * 8 + rb) * 32 + ri];
        w_out[(size_t)(b0 + rb) * DIM + i0 + ri] =
            (sm + b_mem[i0 + ri]) * s1 + s2;
    }
}

// ---------------------------------------------------------------------------
// Kernel 2: per-b streaming pass over know (float4, 16 waves/block).
// (byte-identical to round 6 — best proven read)
// ---------------------------------------------------------------------------
__global__ __launch_bounds__(1024) void read_kernel(
    const float* __restrict__ know,  // (BB, DIM, NN)
    const float* __restrict__ w,     // (BB, DIM)
    float* __restrict__ out)         // (BB, NN)
{
    __shared__ float  w_s[DIM];
    __shared__ float4 part_lg[16][50];
    __shared__ float4 part_ks[16][50];
    __shared__ float  tmp[256];
    __shared__ float  bc[2];

    const int tx  = threadIdx.x;       // 0..63 (lane)
    const int ty  = threadIdx.y;       // 0..15 (wave)
    const int tid = ty * 64 + tx;
    const int b   = blockIdx.x;

    if (tid < DIM) w_s[tid] = w[(size_t)b * DIM + tid];
    __syncthreads();

    float4 lg = make_float4(0.f, 0.f, 0.f, 0.f);
    float4 ks = make_float4(0.f, 0.f, 0.f, 0.f);
    if (tx < 49) {
        const float4* kp = (const float4*)(know + (size_t)b * DIM * NN) + (size_t)(ty * 32) * 49 + tx;
        const float*  wp = w_s + ty * 32;
        #pragma unroll 8
        for (int dd = 0; dd < 32; ++dd) {
            const float4 kv = kp[(size_t)dd * 49];
            const float  wv = wp[dd];
            lg.x = fmaf(kv.x, wv, lg.x); lg.y = fmaf(kv.y, wv, lg.y);
            lg.z = fmaf(kv.z, wv, lg.z); lg.w = fmaf(kv.w, wv, lg.w);
            ks.x += kv.x; ks.y += kv.y; ks.z += kv.z; ks.w += kv.w;
        }
        part_lg[ty][tx] = lg;
        part_ks[ty][tx] = ks;
    }
    __syncthreads();

    float lgn = 0.f, ksn = 0.f;
    if (tid < NN) {
        const int ng = tid >> 2, j = tid & 3;
        #pragma unroll
        for (int t = 0; t < 16; ++t) {
            lgn += ((const float*)&part_lg[t][ng])[j];
            ksn += ((const float*)&part_ks[t][ng])[j];
        }
    }

    if (tid < 256) tmp[tid] = (tid < NN) ? lgn : -FLT_MAX;
    __syncthreads();
    if (tid < 64) {
        float m = fmaxf(fmaxf(tmp[tid], tmp[tid + 64]),
                        fmaxf(tmp[tid + 128], tmp[tid + 192]));
        #pragma unroll
        for (int o = 32; o; o >>= 1) m = fmaxf(m, __shfl_down(m, o));
        if (tid == 0) bc[0] = m;
    }
    __syncthreads();

    const float e = (tid < NN) ? __expf(lgn - bc[0]) : 0.f;
    if (tid < 256) tmp[tid] = e;
    __syncthreads();
    if (tid < 64) {
        float s = tmp[tid] + tmp[tid + 64] + tmp[tid + 128] + tmp[tid + 192];
        #pragma unroll
        for (int o = 32; o; o >>= 1) s += __shfl_down(s, o);
        if (tid == 0) bc[1] = s;
    }
    __syncthreads();

    if (tid < NN) out[(size_t)b * NN + tid] = e / bc[1] * ksn;
}

// ---------------------------------------------------------------------------
extern "C" void kernel_launch(void* const* d_in, const int* in_sizes, int n_in,
                              void* d_out, int out_size, void* d_ws, size_t ws_size,
                              hipStream_t stream) {
    const float* memory   = (const float*)d_in[0];
    const float* know     = (const float*)d_in[1];
    const float* control  = (const float*)d_in[2];
    const float* W_mem    = (const float*)d_in[3];
    const float* b_mem    = (const float*)d_in[4];
    const float* W_concat = (const float*)d_in[5];
    // d_in[6] = b_concat : uniform over n -> softmax-invariant, unused
    const float* W_attn   = (const float*)d_in[7];
    // d_in[8] = b_attn   : same, unused
    float* w_ws = (float*)d_ws;          // (BB, DIM) = 512 KB scratch
    float* outp = (float*)d_out;         // (BB, NN) f32

    prep_kernel<<<dim3(BB / BT, DIM / IT), dim3(512), 0, stream>>>(
        memory, control, W_mem, b_mem, W_concat, W_attn, w_ws);
    read_kernel<<<dim3(BB), dim3(64, 16), 0, stream>>>(know, w_ws, outp);
}

// Round 11
// 36.532 us; speedup vs baseline: 3.4039x; 1.3585x over previous
//
#include <hip/hip_runtime.h>
#include <cfloat>

// Problem dims (fixed by reference)
#define BB   256   // batch
#define DIM  512
#define NN   196
#define BT   8     // b-tile in prep kernel
#define IT   32    // i-tile in prep kernel

// ---------------------------------------------------------------------------
// Kernel 1: prep v4 — w[b,i] = (mem[b,i] + b_mem[i]) * v1[b,i] + v2[b,i]
//   mem[b,i] = sum_k memory[-1][b,k] * W_mem[k,i]
//   v1[b,i]  = sum_k u[b,k] * W_concat[i,     k]   (u = control[-1]*W_attn)
//   v2[b,i]  = sum_k u[b,k] * W_concat[DIM+i, k]
//
// r6-prep measured 15us @ 1 block/CU (112KB LDS): ~6us VALU + ~8us
// barrier-exposed global latency (cold caches each replay). Fixes here:
//   (a) BT=8 -> LDS 80 KB (MU4 32K + 48K union) -> 2 blocks/CU, barriers
//       of one block hide under the other's compute;
//   (b) register prefetch: chunk t+1's W_concat f4s AND W_mem column loaded
//       into regs during chunk t's compute (issue-early / write-late), so
//       barriers never wait on fresh global loads.
// grid (32,16) = 512 blocks x 512 thr. Thread (il=tid&31, kg=tid>>5):
// 4-k slice per 64-k chunk, one i, 8 b -> 24 accumulators.
// ---------------------------------------------------------------------------
__global__ __launch_bounds__(512, 4) void prep_kernel(
    const float* __restrict__ memory,    // (2,BB,DIM)
    const float* __restrict__ control,   // (2,BB,DIM)
    const float* __restrict__ W_mem,     // (DIM,DIM) row-major [k][i]
    const float* __restrict__ b_mem,     // (DIM)
    const float* __restrict__ W_concat,  // (2*DIM, DIM) row-major [c][j]
    const float* __restrict__ W_attn,    // (DIM,1)
    float* __restrict__ w_out)           // (BB, DIM)
{
    // MU4[p][k] = (m[b0+2p][k], u[b0+2p][k], m[b0+2p+1][k], u[b0+2p+1][k])
    __shared__ float4 MU4[4][DIM];   // 32 KB
    // union: WT float2[64][33] (16.9 KB) during chunks; epilogue P[3][128][32]
    __shared__ float  buf[12288];    // 48 KB

    const int tid = threadIdx.x;
    const int il  = tid & 31;          // i within tile
    const int kg  = tid >> 5;          // 0..15, owns k-slice kg*4..kg*4+3
    const int b0  = blockIdx.x * BT;
    const int i0  = blockIdx.y * IT;

    const float* mem_in = memory  + (size_t)BB * DIM;  // memory[-1]
    const float* ctl_in = control + (size_t)BB * DIM;  // control[-1]

    // ---- stage MU4 once: k = tid, coalesced over k ----
    {
        const float wa = W_attn[tid];
        #pragma unroll
        for (int p = 0; p < 4; ++p) {
            MU4[p][tid] = make_float4(
                mem_in[(size_t)(b0 + 2 * p)     * DIM + tid],
                ctl_in[(size_t)(b0 + 2 * p)     * DIM + tid] * wa,
                mem_in[(size_t)(b0 + 2 * p + 1) * DIM + tid],
                ctl_in[(size_t)(b0 + 2 * p + 1) * DIM + tid] * wa);
        }
    }

    float am[8] = {0,0,0,0,0,0,0,0};
    float a1[8] = {0,0,0,0,0,0,0,0};
    float a2[8] = {0,0,0,0,0,0,0,0};

    // staging coords: sr = i row, sc = float4 col of the 64-k chunk
    const int sr = tid >> 4;           // 0..31
    const int sc = tid & 15;           // 0..15
    float2* WT = (float2*)buf;

    // ---- prefetch chunk 0 into regs ----
    float4 f1 = *(const float4*)&W_concat[(size_t)(i0 + sr) * DIM + sc * 4];
    float4 f2 = *(const float4*)&W_concat[(size_t)(DIM + i0 + sr) * DIM + sc * 4];
    float wmc[4], wmn[4];
    #pragma unroll
    for (int j = 0; j < 4; ++j)
        wmc[j] = W_mem[(size_t)(kg * 4 + j) * DIM + i0 + il];

    for (int kt = 0; kt < DIM; kt += 64) {
        __syncthreads();   // prev chunk's compute done; WT free; MU4 ready

        // write prefetched W_concat regs -> WT (transposed, (c1,c2) pairs)
        {
            const float* f1f = (const float*)&f1;
            const float* f2f = (const float*)&f2;
            #pragma unroll
            for (int j = 0; j < 4; ++j)
                WT[(sc * 4 + j) * 33 + sr] = make_float2(f1f[j], f2f[j]);
        }
        // issue next chunk's W_concat loads (hide under this chunk's compute)
        if (kt + 64 < DIM) {
            f1 = *(const float4*)&W_concat[(size_t)(i0 + sr) * DIM + kt + 64 + sc * 4];
            f2 = *(const float4*)&W_concat[(size_t)(DIM + i0 + sr) * DIM + kt + 64 + sc * 4];
        }
        __syncthreads();

        // issue next chunk's W_mem loads early, then compute current chunk
        if (kt + 64 < DIM) {
            #pragma unroll
            for (int j = 0; j < 4; ++j)
                wmn[j] = W_mem[(size_t)(kt + 64 + kg * 4 + j) * DIM + i0 + il];
        }

        #pragma unroll
        for (int j = 0; j < 4; ++j) {
            const int kl = kg * 4 + j;
            const int k  = kt + kl;
            const float2 c = WT[kl * 33 + il];   // lane b64, ~2-way max
            #pragma unroll
            for (int p = 0; p < 4; ++p) {
                const float4 mu = MU4[p][k];     // broadcast b128
                am[2 * p]     = fmaf(mu.x, wmc[j], am[2 * p]);
                a1[2 * p]     = fmaf(mu.y, c.x,    a1[2 * p]);
                a2[2 * p]     = fmaf(mu.y, c.y,    a2[2 * p]);
                am[2 * p + 1] = fmaf(mu.z, wmc[j], am[2 * p + 1]);
                a1[2 * p + 1] = fmaf(mu.w, c.x,    a1[2 * p + 1]);
                a2[2 * p + 1] = fmaf(mu.w, c.y,    a2[2 * p + 1]);
            }
        }
        #pragma unroll
        for (int j = 0; j < 4; ++j) wmc[j] = wmn[j];
    }

    // ---- epilogue: single-phase partial dump (48 KB), one reduce ----
    __syncthreads();
    #pragma unroll
    for (int b = 0; b < 8; ++b) {
        const int row = (kg * 8 + b) * 32 + il;   // banks = il -> conflict-free
        buf[row]        = am[b];
        buf[4096 + row] = a1[b];
        buf[8192 + row] = a2[b];
    }
    __syncthreads();
    if (tid < 256) {
        const int rb = tid >> 5, ri = tid & 31;
        float sm = 0.f, s1 = 0.f, s2 = 0.f;
        #pragma unroll
        for (int t = 0; t < 16; ++t) {
            const int row = (t * 8 + rb) * 32 + ri;
            sm += buf[row];
            s1 += buf[4096 + row];
            s2 += buf[8192 + row];
        }
        w_out[(size_t)(b0 + rb) * DIM + i0 + ri] =
            (sm + b_mem[i0 + ri]) * s1 + s2;
    }
}

// ---------------------------------------------------------------------------
// Kernel 2: per-b streaming pass over know (float4, 16 waves/block).
// (byte-identical to round 6 — best proven read)
// ---------------------------------------------------------------------------
__global__ __launch_bounds__(1024) void read_kernel(
    const float* __restrict__ know,  // (BB, DIM, NN)
    const float* __restrict__ w,     // (BB, DIM)
    float* __restrict__ out)         // (BB, NN)
{
    __shared__ float  w_s[DIM];
    __shared__ float4 part_lg[16][50];
    __shared__ float4 part_ks[16][50];
    __shared__ float  tmp[256];
    __shared__ float  bc[2];

    const int tx  = threadIdx.x;       // 0..63 (lane)
    const int ty  = threadIdx.y;       // 0..15 (wave)
    const int tid = ty * 64 + tx;
    const int b   = blockIdx.x;

    if (tid < DIM) w_s[tid] = w[(size_t)b * DIM + tid];
    __syncthreads();

    float4 lg = make_float4(0.f, 0.f, 0.f, 0.f);
    float4 ks = make_float4(0.f, 0.f, 0.f, 0.f);
    if (tx < 49) {
        const float4* kp = (const float4*)(know + (size_t)b * DIM * NN) + (size_t)(ty * 32) * 49 + tx;
        const float*  wp = w_s + ty * 32;
        #pragma unroll 8
        for (int dd = 0; dd < 32; ++dd) {
            const float4 kv = kp[(size_t)dd * 49];
            const float  wv = wp[dd];
            lg.x = fmaf(kv.x, wv, lg.x); lg.y = fmaf(kv.y, wv, lg.y);
            lg.z = fmaf(kv.z, wv, lg.z); lg.w = fmaf(kv.w, wv, lg.w);
            ks.x += kv.x; ks.y += kv.y; ks.z += kv.z; ks.w += kv.w;
        }
        part_lg[ty][tx] = lg;
        part_ks[ty][tx] = ks;
    }
    __syncthreads();

    float lgn = 0.f, ksn = 0.f;
    if (tid < NN) {
        const int ng = tid >> 2, j = tid & 3;
        #pragma unroll
        for (int t = 0; t < 16; ++t) {
            lgn += ((const float*)&part_lg[t][ng])[j];
            ksn += ((const float*)&part_ks[t][ng])[j];
        }
    }

    if (tid < 256) tmp[tid] = (tid < NN) ? lgn : -FLT_MAX;
    __syncthreads();
    if (tid < 64) {
        float m = fmaxf(fmaxf(tmp[tid], tmp[tid + 64]),
                        fmaxf(tmp[tid + 128], tmp[tid + 192]));
        #pragma unroll
        for (int o = 32; o; o >>= 1) m = fmaxf(m, __shfl_down(m, o));
        if (tid == 0) bc[0] = m;
    }
    __syncthreads();

    const float e = (tid < NN) ? __expf(lgn - bc[0]) : 0.f;
    if (tid < 256) tmp[tid] = e;
    __syncthreads();
    if (tid < 64) {
        float s = tmp[tid] + tmp[tid + 64] + tmp[tid + 128] + tmp[tid + 192];
        #pragma unroll
        for (int o = 32; o; o >>= 1) s += __shfl_down(s, o);
        if (tid == 0) bc[1] = s;
    }
    __syncthreads();

    if (tid < NN) out[(size_t)b * NN + tid] = e / bc[1] * ksn;
}

// ---------------------------------------------------------------------------
extern "C" void kernel_launch(void* const* d_in, const int* in_sizes, int n_in,
                              void* d_out, int out_size, void* d_ws, size_t ws_size,
                              hipStream_t stream) {
    const float* memory   = (const float*)d_in[0];
    const float* know     = (const float*)d_in[1];
    const float* control  = (const float*)d_in[2];
    const float* W_mem    = (const float*)d_in[3];
    const float* b_mem    = (const float*)d_in[4];
    const float* W_concat = (const float*)d_in[5];
    // d_in[6] = b_concat : uniform over n -> softmax-invariant, unused
    const float* W_attn   = (const float*)d_in[7];
    // d_in[8] = b_attn   : same, unused
    float* w_ws = (float*)d_ws;          // (BB, DIM) = 512 KB scratch
    float* outp = (float*)d_out;         // (BB, NN) f32

    prep_kernel<<<dim3(BB / BT, DIM / IT), dim3(512), 0, stream>>>(
        memory, control, W_mem, b_mem, W_concat, W_attn, w_ws);
    read_kernel<<<dim3(BB), dim3(64, 16), 0, stream>>>(know, w_ws, outp);
}